// Round 2
// baseline (146.635 us; speedup 1.0000x reference)
//
#include <hip/hip_runtime.h>

// Problem constants (from reference setup_inputs)
#define QDIM 900
#define CDIM 80
#define TDIM 300
#define QPB 36               // q's per block (4 waves x 9)
#define QPW 9                // q's per wave
#define NQB (QDIM / QPB)     // 25 blocks per batch
#define NSLICE 5             // ceil(300/64)

__global__ __launch_bounds__(256) void matcher_cost_kernel(
    const float* __restrict__ pred_logits,  // [B,Q,C]
    const float* __restrict__ pred_boxes,   // [B,Q,4] cxcywh
    const int*   __restrict__ tgt_labels,   // [B,T]
    const float* __restrict__ tgt_boxes,    // [B,T,4] cxcywh
    float* __restrict__ out)                // [B,Q,T]
{
    // s_cls[ql*C + c] = 2 - 2*sigmoid(logit) = 2/(1+e^x)
    // (the +2 comes from folding giou = iou - 1 + uni/areac)
    __shared__ float s_cls[QPB * CDIM];     // 11.25 KB

    const int tid = threadIdx.x;
    const int b  = blockIdx.x / NQB;
    const int q0 = (blockIdx.x % NQB) * QPB;

    const float* lg = pred_logits + ((size_t)b * QDIM + q0) * CDIM;
    for (int i = tid; i < QPB * CDIM; i += 256) {
        float x = lg[i];
        s_cls[i] = 2.0f * __builtin_amdgcn_rcpf(1.0f + __expf(x));
    }
    __syncthreads();

    const int wave = tid >> 6;
    const int lane = tid & 63;

    // ---- per-lane target slices in REGISTERS: t = lane + 64k, k = 0..4 ----
    float bx0[NSLICE], by0[NSLICE], bx1[NSLICE], by1[NSLICE];
    float bcx[NSLICE], bcy[NSLICE], bw[NSLICE], bh[NSLICE], barea[NSLICE];
    int   lab[NSLICE];
    {
        const float4* tb4 = reinterpret_cast<const float4*>(tgt_boxes) + (size_t)b * TDIM;
        const int*    lb  = tgt_labels + (size_t)b * TDIM;
        #pragma unroll
        for (int k = 0; k < NSLICE; ++k) {
            int t = lane + 64 * k;
            if (t > TDIM - 1) t = TDIM - 1;    // clamp: loads valid, store predicated
            float4 v = tb4[t];
            bcx[k] = v.x; bcy[k] = v.y; bw[k] = v.z; bh[k] = v.w;
            float hw = 0.5f * v.z, hh = 0.5f * v.w;
            bx0[k] = v.x - hw; by0[k] = v.y - hh;
            bx1[k] = v.x + hw; by1[k] = v.y + hh;
            barea[k] = v.z * v.w;
            lab[k] = lb[t];
        }
    }
    const bool tail_ok = lane < (TDIM - 64 * (NSLICE - 1));   // lane < 44

    // ---- q loop: wave owns 9 contiguous q's ----
    const int qw = q0 + wave * QPW;
    const float4* pb4 = reinterpret_cast<const float4*>(pred_boxes) + (size_t)b * QDIM + qw;
    float* obase = out + ((size_t)b * QDIM + qw) * TDIM + lane;

    #pragma unroll 3
    for (int j = 0; j < QPW; ++j) {
        float4 a = pb4[j];
        const float hw = 0.5f * a.z, hh = 0.5f * a.w;
        const float ax0 = a.x - hw, ay0 = a.y - hh;
        const float ax1 = a.x + hw, ay1 = a.y + hh;
        const float area_a = a.z * a.w;
        const int clsrow = (wave * QPW + j) * CDIM;   // element index into s_cls
        float* po = obase + j * TDIM;

        #pragma unroll
        for (int k = 0; k < NSLICE; ++k) {
            float clsv = s_cls[clsrow + lab[k]];

            // intersection
            float ix0 = fmaxf(ax0, bx0[k]), iy0 = fmaxf(ay0, by0[k]);
            float ix1 = fminf(ax1, bx1[k]), iy1 = fminf(ay1, by1[k]);
            float iw = fmaxf(ix1 - ix0, 0.0f), ih = fmaxf(iy1 - iy0, 0.0f);
            float inter = iw * ih;
            float uni = (area_a + barea[k]) - inter;

            // enclosing box
            float cx0 = fminf(ax0, bx0[k]), cy0 = fminf(ay0, by0[k]);
            float cx1 = fmaxf(ax1, bx1[k]), cy1 = fmaxf(ay1, by1[k]);
            float areac = (cx1 - cx0) * (cy1 - cy0);

            // L1 in cxcywh
            float l1 = fabsf(a.x - bcx[k]) + fabsf(a.y - bcy[k])
                     + fabsf(a.z - bw[k])  + fabsf(a.w - bh[k]);

            // cost = (2 - 2*sig) + 5*l1 - 2*inter/uni - 2*uni/areac
            float acc = fmaf(5.0f, l1, clsv);
            acc = fmaf(-2.0f * inter, __builtin_amdgcn_rcpf(uni),   acc);
            acc = fmaf(-2.0f * uni,   __builtin_amdgcn_rcpf(areac), acc);

            if (k < NSLICE - 1 || tail_ok)
                po[64 * k] = acc;
        }
    }
}

extern "C" void kernel_launch(void* const* d_in, const int* in_sizes, int n_in,
                              void* d_out, int out_size, void* d_ws, size_t ws_size,
                              hipStream_t stream) {
    const float* pred_logits = (const float*)d_in[0];
    const float* pred_boxes  = (const float*)d_in[1];
    const int*   tgt_labels  = (const int*)d_in[2];
    const float* tgt_boxes   = (const float*)d_in[3];
    float* out = (float*)d_out;

    const int B = in_sizes[0] / (QDIM * CDIM);   // 256
    dim3 grid(B * NQB);                          // 256 * 25 = 6400
    dim3 block(256);
    matcher_cost_kernel<<<grid, block, 0, stream>>>(pred_logits, pred_boxes,
                                                    tgt_labels, tgt_boxes, out);
}

// Round 3
// 88.240 us; speedup vs baseline: 1.6618x; 1.6618x over previous
//
#include <hip/hip_runtime.h>

// Problem constants (from reference setup_inputs)
#define QDIM 900
#define CDIM 80
#define TDIM 300
#define QPB 36               // q's per block (4 waves x 9)
#define QPW 9                // q's per wave
#define NQB (QDIM / QPB)     // 25 blocks per batch
#define NSLICE 5             // ceil(300/64)

__global__ __launch_bounds__(256, 4) void matcher_cost_kernel(
    const float* __restrict__ pred_logits,  // [B,Q,C]
    const float* __restrict__ pred_boxes,   // [B,Q,4] cxcywh
    const int*   __restrict__ tgt_labels,   // [B,T]
    const float* __restrict__ tgt_boxes,    // [B,T,4] cxcywh
    float* __restrict__ out)                // [B,Q,T]
{
    // s_cls[ql*C + c] = 2 - 2*sigmoid(logit) = 2/(1+e^x)
    // (the +2 comes from folding giou = iou - 1 + uni/areac)
    __shared__ float s_cls[QPB * CDIM];     // 11.25 KB

    const int tid = threadIdx.x;
    const int b  = blockIdx.x / NQB;
    const int q0 = (blockIdx.x % NQB) * QPB;

    const float* lg = pred_logits + ((size_t)b * QDIM + q0) * CDIM;
    for (int i = tid; i < QPB * CDIM; i += 256) {
        float x = lg[i];
        s_cls[i] = 2.0f * __builtin_amdgcn_rcpf(1.0f + __expf(x));
    }
    __syncthreads();

    const int wave = tid >> 6;
    const int lane = tid & 63;

    // ---- per-lane target slices in REGISTERS: t = lane + 64k, k = 0..4 ----
    float bx0[NSLICE], by0[NSLICE], bx1[NSLICE], by1[NSLICE];
    float bcx[NSLICE], bcy[NSLICE], bw[NSLICE], bh[NSLICE], barea[NSLICE];
    int   labb[NSLICE];   // byte offset of label (pre-shifted)
    {
        const float4* tb4 = reinterpret_cast<const float4*>(tgt_boxes) + (size_t)b * TDIM;
        const int*    lb  = tgt_labels + (size_t)b * TDIM;
        #pragma unroll
        for (int k = 0; k < NSLICE; ++k) {
            int t = lane + 64 * k;
            if (t > TDIM - 1) t = TDIM - 1;    // clamp: loads valid, store predicated
            float4 v = tb4[t];
            bcx[k] = v.x; bcy[k] = v.y; bw[k] = v.z; bh[k] = v.w;
            float hw = 0.5f * v.z, hh = 0.5f * v.w;
            bx0[k] = v.x - hw; by0[k] = v.y - hh;
            bx1[k] = v.x + hw; by1[k] = v.y + hh;
            barea[k] = v.z * v.w;
            labb[k] = lb[t];
        }
    }
    const bool tail_ok = lane < (TDIM - 64 * (NSLICE - 1));   // lane < 44

    // ---- q loop: wave owns 9 contiguous q's ----
    const int qw = q0 + wave * QPW;
    const float4* pb4 = reinterpret_cast<const float4*>(pred_boxes) + (size_t)b * QDIM + qw;
    float* obase = out + ((size_t)b * QDIM + qw) * TDIM + lane;

    #pragma unroll 1
    for (int j = 0; j < QPW; ++j) {
        float4 a = pb4[j];
        const float hw = 0.5f * a.z, hh = 0.5f * a.w;
        const float ax0 = a.x - hw, ay0 = a.y - hh;
        const float ax1 = a.x + hw, ay1 = a.y + hh;
        const float area_a = a.z * a.w;
        const float* clsrow = s_cls + (wave * QPW + j) * CDIM;
        float* po = obase + j * TDIM;

        #pragma unroll
        for (int k = 0; k < NSLICE; ++k) {
            float clsv = clsrow[labb[k]];

            // intersection
            float ix0 = fmaxf(ax0, bx0[k]), iy0 = fmaxf(ay0, by0[k]);
            float ix1 = fminf(ax1, bx1[k]), iy1 = fminf(ay1, by1[k]);
            float iw = fmaxf(ix1 - ix0, 0.0f), ih = fmaxf(iy1 - iy0, 0.0f);
            float inter = iw * ih;
            float uni = (area_a + barea[k]) - inter;

            // enclosing box
            float cx0 = fminf(ax0, bx0[k]), cy0 = fminf(ay0, by0[k]);
            float cx1 = fmaxf(ax1, bx1[k]), cy1 = fmaxf(ay1, by1[k]);
            float areac = (cx1 - cx0) * (cy1 - cy0);

            // L1 in cxcywh
            float l1 = fabsf(a.x - bcx[k]) + fabsf(a.y - bcy[k])
                     + fabsf(a.z - bw[k])  + fabsf(a.w - bh[k]);

            // cost = (2 - 2*sig) + 5*l1 - 2*(inter/uni + uni/areac)
            float r = inter * __builtin_amdgcn_rcpf(uni);
            r = fmaf(uni, __builtin_amdgcn_rcpf(areac), r);
            float acc = fmaf(5.0f, l1, clsv);
            acc = fmaf(-2.0f, r, acc);

            if (k < NSLICE - 1 || tail_ok)
                __builtin_nontemporal_store(acc, po + 64 * k);
        }
    }
}

extern "C" void kernel_launch(void* const* d_in, const int* in_sizes, int n_in,
                              void* d_out, int out_size, void* d_ws, size_t ws_size,
                              hipStream_t stream) {
    const float* pred_logits = (const float*)d_in[0];
    const float* pred_boxes  = (const float*)d_in[1];
    const int*   tgt_labels  = (const int*)d_in[2];
    const float* tgt_boxes   = (const float*)d_in[3];
    float* out = (float*)d_out;

    const int B = in_sizes[0] / (QDIM * CDIM);   // 256
    dim3 grid(B * NQB);                          // 256 * 25 = 6400
    dim3 block(256);
    matcher_cost_kernel<<<grid, block, 0, stream>>>(pred_logits, pred_boxes,
                                                    tgt_labels, tgt_boxes, out);
}